// Round 6
// baseline (113.460 us; speedup 1.0000x reference)
//
#include <hip/hip_runtime.h>
#include <math.h>

typedef __bf16 bf16x8 __attribute__((ext_vector_type(8)));
typedef float  f32x4  __attribute__((ext_vector_type(4)));

// Bit-exact fp32 -> (hi,lo) bf16 split (integer-domain truncation; Sterbenz
// subtract). x ≈ hi + lo with residual <= ~2^-17 |x|.
__device__ inline void split_bits(float x, __bf16& h, __bf16& l) {
    unsigned u = __builtin_bit_cast(unsigned, x);
    h = __builtin_bit_cast(__bf16, (unsigned short)(u >> 16));
    float hf = __builtin_bit_cast(float, u & 0xFFFF0000u);
    l = (__bf16)(x - hf);
}

// ---------------------------------------------------------------------------
// S0: split W1 (fp32 [K][N]) into transposed bf16 hi/lo: W1t*[n*K + k].
// ---------------------------------------------------------------------------
__global__ __launch_bounds__(256) void s0_split_w1(
    const float* __restrict__ W1, __bf16* __restrict__ Wth,
    __bf16* __restrict__ Wtl, int Dn)
{
    __shared__ float tile[32][33];
    const int k0 = blockIdx.x * 32;
    const int n0 = blockIdx.y * 32;
    const int tx = threadIdx.x & 31, ty = threadIdx.x >> 5;  // ty 0..7
    #pragma unroll
    for (int p = 0; p < 4; ++p)
        tile[ty + p * 8][tx] = W1[(size_t)(k0 + ty + p * 8) * Dn + n0 + tx];
    __syncthreads();
    #pragma unroll
    for (int p = 0; p < 4; ++p) {
        const int n = n0 + ty + p * 8, k = k0 + tx;
        float x = tile[tx][ty + p * 8];
        __bf16 h, l;
        split_bits(x, h, l);
        Wth[(size_t)n * Dn + k] = h;
        Wtl[(size_t)n * Dn + k] = l;
    }
}

// ---------------------------------------------------------------------------
// K1: MFMA split-bf16 GEMM (3-term: hh + hl + lh), fused gelu*W2 row-partial
// epilogue. Tile 64x128 (BM shrunk 128->64 for 2x grid = 6 blocks/CU, LDS
// 30.7 KB -> 5 blocks/CU LDS cap), BK=32, 256 threads (4 waves 2x2, each
// 32 rows x 64 cols). LDS rows padded to 40 bf16 (80 B) - conflict-free.
// ---------------------------------------------------------------------------
#define BM 64
#define BN 128
#define BK 32
#define LDA 40   // padded LDS row stride in bf16 elements (80 B)
#define NT2 12   // partial slots per row = (D/BN) * 2 wave-columns

__device__ inline float gelu_f(float x) {
    return 0.5f * x * (1.0f + erff(x * 0.70710678118654752f));
}

__global__ __launch_bounds__(256, 4) void k1_mfma(
    const float* __restrict__ X, const __bf16* __restrict__ W1th,
    const __bf16* __restrict__ W1tl, const float* __restrict__ b1,
    const float* __restrict__ W2, float* __restrict__ partial,
    int Kd)
{
    __shared__ __bf16 Ash[BM * LDA];
    __shared__ __bf16 Asl[BM * LDA];
    __shared__ __bf16 Bsh[BN * LDA];
    __shared__ __bf16 Bsl[BN * LDA];

    const int t    = threadIdx.x;
    const int lane = t & 63;
    const int w    = t >> 6;
    const int wr   = w >> 1, wc = w & 1;           // 2x2 waves: 32-row x 64-col
    const int ln15 = lane & 15, lg = lane >> 4;
    const int m0   = blockIdx.x * BM;
    const int n0   = blockIdx.y * BN;

    // A staging: thread owns row (t>>2), 8 consecutive k at (t&3)*8
    const int asr = t >> 2, asc = (t & 3) * 8;
    // B staging: thread owns row (t>>1), 16 consecutive k at (t&1)*16
    const int bsr = t >> 1, bsc = (t & 1) * 16;

    f32x4 acc[2][4];
    #pragma unroll
    for (int i = 0; i < 2; ++i)
        #pragma unroll
        for (int j = 0; j < 4; ++j)
            acc[i][j] = (f32x4){0.f, 0.f, 0.f, 0.f};

    for (int k0 = 0; k0 < Kd; k0 += BK) {
        // ---- stage A: fp32 -> hi/lo bf16 via bit split (8 floats/thread) ----
        const float* xsrc = X + (size_t)(m0 + asr) * Kd + k0 + asc;
        float xs[8];
        *(float4*)&xs[0] = *(const float4*)(xsrc + 0);
        *(float4*)&xs[4] = *(const float4*)(xsrc + 4);
        bf16x8 ah, al;
        #pragma unroll
        for (int i = 0; i < 8; ++i) {
            __bf16 h, l;
            split_bits(xs[i], h, l);
            ah[i] = h; al[i] = l;
        }
        *(bf16x8*)&Ash[asr * LDA + asc] = ah;
        *(bf16x8*)&Asl[asr * LDA + asc] = al;

        // ---- stage B: pre-split bf16, straight copy (32 bf16/thread) ----
        const __bf16* bh = W1th + (size_t)(n0 + bsr) * Kd + k0 + bsc;
        const __bf16* bl = W1tl + (size_t)(n0 + bsr) * Kd + k0 + bsc;
        *(bf16x8*)&Bsh[bsr * LDA + bsc]     = *(const bf16x8*)(bh);
        *(bf16x8*)&Bsh[bsr * LDA + bsc + 8] = *(const bf16x8*)(bh + 8);
        *(bf16x8*)&Bsl[bsr * LDA + bsc]     = *(const bf16x8*)(bl);
        *(bf16x8*)&Bsl[bsr * LDA + bsc + 8] = *(const bf16x8*)(bl + 8);

        __syncthreads();

        bf16x8 fah[2], fal[2], fbh[4], fbl[4];
        #pragma unroll
        for (int mf = 0; mf < 2; ++mf) {
            const int r = (wr * 32 + mf * 16 + ln15) * LDA + lg * 8;
            fah[mf] = *(const bf16x8*)&Ash[r];
            fal[mf] = *(const bf16x8*)&Asl[r];
        }
        #pragma unroll
        for (int nf = 0; nf < 4; ++nf) {
            const int r = (wc * 64 + nf * 16 + ln15) * LDA + lg * 8;
            fbh[nf] = *(const bf16x8*)&Bsh[r];
            fbl[nf] = *(const bf16x8*)&Bsl[r];
        }
        #pragma unroll
        for (int mf = 0; mf < 2; ++mf)
            #pragma unroll
            for (int nf = 0; nf < 4; ++nf) {
                acc[mf][nf] = __builtin_amdgcn_mfma_f32_16x16x32_bf16(
                    fah[mf], fbh[nf], acc[mf][nf], 0, 0, 0);
                acc[mf][nf] = __builtin_amdgcn_mfma_f32_16x16x32_bf16(
                    fah[mf], fbl[nf], acc[mf][nf], 0, 0, 0);
                acc[mf][nf] = __builtin_amdgcn_mfma_f32_16x16x32_bf16(
                    fal[mf], fbh[nf], acc[mf][nf], 0, 0, 0);
            }
        __syncthreads();
    }

    // ---- epilogue: per-row sum of gelu(c + b1)*W2 over THIS WAVE's 64 cols.
    float b1v[4], w2v[4];
    #pragma unroll
    for (int nf = 0; nf < 4; ++nf) {
        const int n = n0 + wc * 64 + nf * 16 + ln15;
        b1v[nf] = b1[n];
        w2v[nf] = W2[n];
    }
    #pragma unroll
    for (int mf = 0; mf < 2; ++mf)
        #pragma unroll
        for (int j = 0; j < 4; ++j) {
            float s = 0.f;
            #pragma unroll
            for (int nf = 0; nf < 4; ++nf) {
                float c = acc[mf][nf][j] + b1v[nf];
                s += gelu_f(c) * w2v[nf];
            }
            s += __shfl_xor(s, 1);
            s += __shfl_xor(s, 2);
            s += __shfl_xor(s, 4);
            s += __shfl_xor(s, 8);
            if (ln15 == 0) {
                const int m = m0 + wr * 32 + mf * 16 + lg * 4 + j;
                partial[(size_t)m * NT2 + blockIdx.y * 2 + wc] = s;
            }
        }
}

// ---------------------------------------------------------------------------
// K2: per-batch reduce partials -> prob; flags (last_valid=1); scan -> bpos.
// ---------------------------------------------------------------------------
__global__ __launch_bounds__(256) void k2_scan(
    const float* __restrict__ partial, const float* __restrict__ lengths,
    const float* __restrict__ b2p,
    float* __restrict__ out_probs, float* __restrict__ out_short,
    float* __restrict__ out_nb, float* __restrict__ out_lens,
    int* __restrict__ bpos, int* __restrict__ nb_arr,
    int S, int K)
{
    const int b = blockIdx.x;
    const int t = threadIdx.x;
    const int len = (int)(lengths[b] * (float)S);
    const float b2 = b2p[0];

    __shared__ int cnt[256];
    __shared__ int flags_s[2048];

    const int RP = S / 256;
    const int base_s = t * RP;
    int local = 0;
    for (int r = 0; r < RP; ++r) {
        int s = base_s + r;
        float sum = b2;
        for (int jt = 0; jt < NT2; ++jt)
            sum += partial[(size_t)(b * S + s) * NT2 + jt];
        float prob = 1.0f / (1.0f + expf(-sum));
        bool v = (s < len);
        out_probs[(size_t)b * S + s] = v ? prob : 0.0f;
        int f = (s == len - 1) ? 1 : ((v && prob > 0.5f) ? 1 : 0);
        flags_s[s] = f;
        local += f;
    }
    cnt[t] = local;
    __syncthreads();
    for (int off = 1; off < 256; off <<= 1) {
        int v = cnt[t];
        int u = (t >= off) ? cnt[t - off] : 0;
        __syncthreads();
        cnt[t] = v + u;
        __syncthreads();
    }
    int excl = cnt[t] - local;
    int total = cnt[255];
    for (int r = 0; r < RP; ++r) {
        int s = base_s + r;
        if (flags_s[s]) { bpos[b * S + excl] = s; ++excl; }
    }
    if (t == 0) {
        nb_arr[b] = total;
        float nbf = (float)total;
        float Kf  = (float)K;
        out_nb[b]   = nbf;
        out_lens[b] = (float)len;
        float sh;
        if (nbf >= Kf - 1.0f)      sh = 1.0f;
        else if (nbf > 0.0f)       sh = (nbf + 1.0f) / Kf;
        else                       sh = 0.0f;
        out_short[b] = sh;
    }
}

// ---------------------------------------------------------------------------
// K3: segment-mean pooling. One block per (b,k); D/4 threads of float4.
// ---------------------------------------------------------------------------
__global__ __launch_bounds__(192) void k3_pool(
    const float* __restrict__ X, const int* __restrict__ bpos,
    const int* __restrict__ nb_arr, float* __restrict__ pooled,
    int S, int D, int K)
{
    const int bk = blockIdx.x;
    const int b  = bk / K;
    const int k  = bk - b * K;
    const int t  = threadIdx.x;
    const int nb = nb_arr[b];

    float4 acc = {0.f, 0.f, 0.f, 0.f};
    if (k < nb) {
        int start = (k == 0) ? 0 : (bpos[b * S + k - 1] + 1);
        int end   = bpos[b * S + k] + 1;
        float cntf = (float)(end - start);
        for (int s = start; s < end; ++s) {
            const float4 v = *(const float4*)&X[((size_t)b * S + s) * D + t * 4];
            acc.x += v.x; acc.y += v.y; acc.z += v.z; acc.w += v.w;
        }
        acc.x /= cntf; acc.y /= cntf; acc.z /= cntf; acc.w /= cntf;
    }
    *(float4*)&pooled[((size_t)b * K + k) * D + t * 4] = acc;
}

// ---------------------------------------------------------------------------
extern "C" void kernel_launch(void* const* d_in, const int* in_sizes, int n_in,
                              void* d_out, int out_size, void* d_ws, size_t ws_size,
                              hipStream_t stream) {
    const float* hidden  = (const float*)d_in[0];
    const float* lengths = (const float*)d_in[1];
    const float* W1      = (const float*)d_in[2];
    const float* b1      = (const float*)d_in[3];
    const float* W2      = (const float*)d_in[4];
    const float* b2      = (const float*)d_in[5];

    const int B = in_sizes[1];
    const int D = in_sizes[3];
    const int S = in_sizes[0] / (B * D);
    const int M = B * S;
    const int K = (out_size - B * S - 3 * B) / (B * D);

    float* out_pooled = (float*)d_out;
    float* out_probs  = out_pooled + (size_t)B * K * D;
    float* out_short  = out_probs + (size_t)B * S;
    float* out_nb     = out_short + B;
    float* out_lens   = out_nb + B;

    // d_ws: partial (M*NT2 f32) + bpos (B*S i32) + nb (B i32)  ~851 KB
    char* wsp = (char*)d_ws;
    float* partial = (float*)wsp; wsp += (size_t)M * NT2 * sizeof(float);
    int*   bpos    = (int*)wsp;   wsp += (size_t)B * S * sizeof(int);
    int*   nb_arr  = (int*)wsp;   wsp += 256;

    // W1 hi/lo splits: stash in the pooled output region (K3 overwrites it
    // at the end of every call); fall back to ws tail if it doesn't fit.
    const size_t wsplit_bytes = 2 * (size_t)D * D * sizeof(__bf16);
    __bf16* W1th;
    if ((size_t)B * K * D * sizeof(float) >= wsplit_bytes) {
        W1th = (__bf16*)out_pooled;
    } else {
        W1th = (__bf16*)wsp;
    }
    __bf16* W1tl = W1th + (size_t)D * D;

    dim3 gs(D / 32, D / 32);
    s0_split_w1<<<gs, 256, 0, stream>>>(W1, W1th, W1tl, D);

    dim3 g1(M / BM, D / BN);
    k1_mfma<<<g1, 256, 0, stream>>>(hidden, W1th, W1tl, b1, W2, partial, D);

    k2_scan<<<B, 256, 0, stream>>>(partial, lengths, b2, out_probs, out_short,
                                   out_nb, out_lens, bpos, nb_arr, S, K);
    k3_pool<<<B * K, D / 4, 0, stream>>>(hidden, bpos, nb_arr, out_pooled, S, D, K);
}